// Round 2
// baseline (3671.304 us; speedup 1.0000x reference)
//
#include <hip/hip_runtime.h>
#include <hip/hip_bf16.h>

#define B_ 32
#define T_ 2000
#define S_ 400
#define C0_ 80
#define H_ 256

static constexpr float NEGV = -1e9f;
static constexpr int NMU  = B_ * T_ * S_;       // 25,600,000
static constexpr int NPI  = 2 * NMU;            // 51,200,000
static constexpr int NWSP = B_ * T_ * H_;       // 16,384,000

// ---------------- conv1d (K=5, SAME) + bias + tanh ----------------------
template<int CIN>
__global__ __launch_bounds__(256)
void conv1d_tanh(const float* __restrict__ x, const float* __restrict__ w,
                 const float* __restrict__ bias, float* __restrict__ y)
{
  constexpr int TT  = 32;        // t rows per block
  constexpr int JW  = TT + 4;    // halo rows (pad 2 each side)
  constexpr int STR = 40;        // padded LDS stride
  __shared__ float xs[CIN * STR];
  const int b   = blockIdx.y;
  const int t0  = blockIdx.x * TT;
  const int tid = threadIdx.x;
  const float* xb = x + (size_t)b * T_ * CIN;
  for (int idx = tid; idx < JW * CIN; idx += 256) {
    int ci = idx % CIN;
    int j  = idx / CIN;
    int t  = t0 - 2 + j;
    xs[ci * STR + j] = (t >= 0 && t < T_) ? xb[(size_t)t * CIN + ci] : 0.f;
  }
  __syncthreads();
  const int co = tid;
  float acc[TT];
#pragma unroll
  for (int i = 0; i < TT; i++) acc[i] = 0.f;
  for (int ci = 0; ci < CIN; ci++) {
    float xv[JW];
    const float4* xp = (const float4*)&xs[ci * STR];
#pragma unroll
    for (int r = 0; r < JW / 4; r++) {
      float4 q = xp[r];
      xv[4*r+0] = q.x; xv[4*r+1] = q.y; xv[4*r+2] = q.z; xv[4*r+3] = q.w;
    }
#pragma unroll
    for (int k = 0; k < 5; k++) {
      float wv = w[((size_t)k * CIN + ci) * H_ + co];
#pragma unroll
      for (int i = 0; i < TT; i++) acc[i] = fmaf(xv[i + k], wv, acc[i]);
    }
  }
  const float bv = bias[co];
#pragma unroll
  for (int i = 0; i < TT; i++) {
    int t = t0 + i;
    if (t < T_) y[((size_t)b * T_ + t) * H_ + co] = tanhf(acc[i] + bv);
  }
}

// ---------------- W[b,t,s] = sum_h Wspec[b,t,h] * src_enc[b,s,h] --------
__global__ __launch_bounds__(256)
void einsum_ts(const float* __restrict__ A, const float* __restrict__ E,
               float* __restrict__ Wg)
{
  constexpr int GT = 128, GS = 64, KC = 16;
  __shared__ float As[KC][GT + 4];
  __shared__ float Bs[KC][GS + 4];
  const int b   = blockIdx.z;
  const int t0  = blockIdx.x * GT;
  const int s0  = blockIdx.y * GS;
  const int tid = threadIdx.x;
  const int tx  = tid & 15;
  const int ty  = tid >> 4;
  float4 acc[8];
#pragma unroll
  for (int i = 0; i < 8; i++) acc[i] = make_float4(0.f, 0.f, 0.f, 0.f);
  const float* Ab = A + (size_t)b * T_ * H_;
  const float* Eb = E + (size_t)b * S_ * H_;
  for (int kc = 0; kc < H_; kc += KC) {
#pragma unroll
    for (int r = 0; r < 2; r++) {
      int f4  = tid + 256 * r;
      int row = f4 >> 2;
      int c4  = f4 & 3;
      int t   = t0 + row;
      float4 v = make_float4(0, 0, 0, 0);
      if (t < T_) v = *(const float4*)&Ab[(size_t)t * H_ + kc + c4 * 4];
      As[c4*4+0][row] = v.x; As[c4*4+1][row] = v.y;
      As[c4*4+2][row] = v.z; As[c4*4+3][row] = v.w;
    }
    {
      int row = tid >> 2;
      int c4  = tid & 3;
      int s   = s0 + row;
      float4 v = make_float4(0, 0, 0, 0);
      if (s < S_) v = *(const float4*)&Eb[(size_t)s * H_ + kc + c4 * 4];
      Bs[c4*4+0][row] = v.x; Bs[c4*4+1][row] = v.y;
      Bs[c4*4+2][row] = v.z; Bs[c4*4+3][row] = v.w;
    }
    __syncthreads();
#pragma unroll
    for (int kk = 0; kk < KC; kk++) {
      float4 a0 = *(const float4*)&As[kk][ty * 8];
      float4 a1 = *(const float4*)&As[kk][ty * 8 + 4];
      float4 bb = *(const float4*)&Bs[kk][tx * 4];
      float av[8] = {a0.x, a0.y, a0.z, a0.w, a1.x, a1.y, a1.z, a1.w};
#pragma unroll
      for (int i = 0; i < 8; i++) {
        acc[i].x = fmaf(av[i], bb.x, acc[i].x);
        acc[i].y = fmaf(av[i], bb.y, acc[i].y);
        acc[i].z = fmaf(av[i], bb.z, acc[i].z);
        acc[i].w = fmaf(av[i], bb.w, acc[i].w);
      }
    }
    __syncthreads();
  }
  float* Wb = Wg + (size_t)b * T_ * S_;
  const int s = s0 + tx * 4;
#pragma unroll
  for (int i = 0; i < 8; i++) {
    int t = t0 + ty * 8 + i;
    if (t < T_ && s < S_) *(float4*)&Wb[(size_t)t * S_ + s] = acc[i];
  }
}

// ---------------- per-(b,s) column softmax stats over T ------------------
// Writes M + ln(L) into mu[b][0][s] (consumed then overwritten by dp).
__global__ __launch_bounds__(256)
void softmax_stats(const float* __restrict__ Wg, float* __restrict__ statsOut)
{
  const int b  = blockIdx.y;
  const int tx = threadIdx.x & 63;
  const int ty = threadIdx.x >> 6;            // 0..3
  const int s  = blockIdx.x * 64 + tx;
  const bool act = (s < S_);
  float m = -1e30f, l = 0.f;
  if (act) {
    const float* col = Wg + (size_t)b * T_ * S_ + s;
#pragma unroll 4
    for (int t = ty; t < T_; t += 4) {
      float v  = col[(size_t)t * S_];
      float nm = fmaxf(m, v);
      l = l * __expf(m - nm) + __expf(v - nm);
      m = nm;
    }
  }
  __shared__ float rm[4][64], rl[4][64];
  rm[ty][tx] = m; rl[ty][tx] = l;
  __syncthreads();
  if (ty == 0 && act) {
    float M = rm[0][tx];
#pragma unroll
    for (int q = 1; q < 4; q++) M = fmaxf(M, rm[q][tx]);
    float L = 0.f;
#pragma unroll
    for (int q = 0; q < 4; q++) L += rl[q][tx] * __expf(rm[q][tx] - M);
    float* st = statsOut + (size_t)b * T_ * S_;
    st[s] = M + __logf(L);                    // single fused stat
  }
}

// ---------------- monotonic-alignment Bayesian DP (1 wave / batch) -------
// Lane l owns s = 7l..7l+6 (blocked). Only one __shfl_up per t-step; no
// barriers, no LDS. Loads clamped to s=399 for the ragged tail lanes
// (values stay bounded: a<=M for the true column => av<=1, no Inf/NaN);
// stores predicated by the true s.
__global__ __launch_bounds__(64)
void dp_kernel2(float* __restrict__ Wal,       // [B,T,S] raw scores in, alignments out
                const float* __restrict__ Mk,  // mask [B,T,S]
                float* __restrict__ muOut,     // [B,T,S]; row 0 carries M+lnL on entry
                float2* __restrict__ piOut)    // [B,T,S,2]
{
  constexpr int CPL = 7;   // cells (s columns) per lane
  constexpr int PF  = 4;   // prefetch depth (t rows)
  const int b = blockIdx.x;
  const int l = threadIdx.x;        // 0..63
  const int s0 = l * CPL;

  float*       alb = Wal   + (size_t)b * T_ * S_;
  const float* kb  = Mk    + (size_t)b * T_ * S_;
  float*       mub = muOut + (size_t)b * T_ * S_;
  float2*      pib = piOut + (size_t)b * T_ * S_;

  int  col[CPL];
  bool val[CPL];
#pragma unroll
  for (int j = 0; j < CPL; j++) {
    int s = s0 + j;
    val[j] = (s < S_);
    col[j] = val[j] ? s : (S_ - 1);
  }

  // stats (M + lnL) — read BEFORE any write to mu row 0
  float Ms[CPL];
#pragma unroll
  for (int j = 0; j < CPL; j++) Ms[j] = mub[col[j]];

  // ---- t = 0 ----
  float m[CPL];
#pragma unroll
  for (int j = 0; j < CPL; j++) {
    float av = __expf(alb[col[j]] - Ms[j]);
    float w  = av * kb[col[j]];
    m[j] = w + ((s0 + j) == 0 ? 0.f : NEGV);
    if (val[j]) {
      alb[col[j]] = av;
      mub[col[j]] = m[j];
      pib[col[j]] = make_float2(1.f, 0.f);
    }
  }

  // ---- prefetch rows 1..PF ----
  float a[PF][CPL], kk[PF][CPL];
#pragma unroll
  for (int p = 0; p < PF; p++) {
    const int trow = 1 + p;
    const float* ra = alb + (size_t)trow * S_;
    const float* rk = kb  + (size_t)trow * S_;
#pragma unroll
    for (int j = 0; j < CPL; j++) { a[p][j] = ra[col[j]]; kk[p][j] = rk[col[j]]; }
  }

  // ---- main loop over t = 1..T-1 ----
  for (int t0 = 1; t0 < T_; t0 += PF) {
#pragma unroll
    for (int p = 0; p < PF; p++) {
      const int t = t0 + p;
      if (t >= T_) break;                      // wave-uniform
      // consume slot p into locals, then refill slot p with row t+PF
      float aj[CPL], kj[CPL];
#pragma unroll
      for (int j = 0; j < CPL; j++) { aj[j] = a[p][j]; kj[j] = kk[p][j]; }
      {
        const int trow = t + PF;
        if (trow < T_) {                       // wave-uniform guard
          const float* ra = alb + (size_t)trow * S_;
          const float* rk = kb  + (size_t)trow * S_;
#pragma unroll
          for (int j = 0; j < CPL; j++) { a[p][j] = ra[col[j]]; kk[p][j] = rk[col[j]]; }
        }
      }
      // cross-lane shift: old m[6] of lane l-1
      float sh = __shfl_up(m[CPL - 1], 1);
      if (l == 0) sh = NEGV;

      float* rowAl = alb + (size_t)t * S_;
      float* rowMu = mub + (size_t)t * S_;
      float2* rowPi = pib + (size_t)t * S_;
      // descending j: m[j-1] still holds the previous-t value when read
#pragma unroll
      for (int j = CPL - 1; j >= 0; j--) {
        float av   = __expf(aj[j] - Ms[j]);
        float w    = av * kj[j];
        float prev = m[j];
        float sft  = (j == 0) ? sh : m[j - 1];
        float d    = prev - sft;
        float e    = __expf(-fabsf(d));
        float q    = 1.f + e;
        float hi   = fmaxf(prev, sft);
        float lg   = __logf(q);
        float r;
        asm("v_rcp_f32 %0, %1" : "=v"(r) : "v"(q));
        float mnew = w + hi + lg;
        float p0   = (d >= 0.f) ? r : 1.f - r;
        if (val[j]) {
          rowAl[col[j]] = av;
          rowMu[col[j]] = mnew;
          rowPi[col[j]] = make_float2(p0, 1.f - p0);
        }
        m[j] = mnew;
      }
    }
  }
}

// -------------------------------------------------------------------------
extern "C" void kernel_launch(void* const* d_in, const int* in_sizes, int n_in,
                              void* d_out, int out_size, void* d_ws, size_t ws_size,
                              hipStream_t stream)
{
  (void)in_sizes; (void)n_in; (void)out_size; (void)d_ws; (void)ws_size;
  const float* x   = (const float*)d_in[0];
  const float* enc = (const float*)d_in[1];
  const float* msk = (const float*)d_in[2];
  const float* w1  = (const float*)d_in[3];
  const float* b1  = (const float*)d_in[4];
  const float* w2  = (const float*)d_in[5];
  const float* b2  = (const float*)d_in[6];
  const float* w3  = (const float*)d_in[7];
  const float* b3  = (const float*)d_in[8];

  float* out = (float*)d_out;
  float* mu  = out;                       // [B,T,S]
  float* pi  = out + NMU;                 // [B,T,S,2]
  float* al  = out + NMU + NPI;           // [B,T,S]
  float* wsp = out + NMU + NPI + NMU;     // [B,T,H]
  float* h1  = pi;                        // scratch inside pi region (written last)
  float* h2  = pi + NWSP;

  dim3 cgrid((T_ + 31) / 32, B_);
  hipLaunchKernelGGL((conv1d_tanh<C0_>), cgrid, dim3(256), 0, stream, x,  w1, b1, h1);
  hipLaunchKernelGGL((conv1d_tanh<H_>),  cgrid, dim3(256), 0, stream, h1, w2, b2, h2);
  hipLaunchKernelGGL((conv1d_tanh<H_>),  cgrid, dim3(256), 0, stream, h2, w3, b3, wsp);
  hipLaunchKernelGGL(einsum_ts, dim3((T_ + 127) / 128, (S_ + 63) / 64, B_), dim3(256),
                     0, stream, wsp, enc, al);
  hipLaunchKernelGGL(softmax_stats, dim3((S_ + 63) / 64, B_), dim3(256), 0, stream, al, mu);
  hipLaunchKernelGGL(dp_kernel2, dim3(B_), dim3(64), 0, stream, al, msk, mu, (float2*)pi);
}

// Round 3
// 3000.022 us; speedup vs baseline: 1.2238x; 1.2238x over previous
//
#include <hip/hip_runtime.h>
#include <hip/hip_bf16.h>

#define B_ 32
#define T_ 2000
#define S_ 400
#define C0_ 80
#define H_ 256

static constexpr float NEGV = -1e9f;
static constexpr int NMU  = B_ * T_ * S_;       // 25,600,000
static constexpr int NPI  = 2 * NMU;            // 51,200,000
static constexpr int NWSP = B_ * T_ * H_;       // 16,384,000

// ---------------- conv1d (K=5, SAME) + bias + tanh ----------------------
template<int CIN>
__global__ __launch_bounds__(256)
void conv1d_tanh(const float* __restrict__ x, const float* __restrict__ w,
                 const float* __restrict__ bias, float* __restrict__ y)
{
  constexpr int TT  = 32;        // t rows per block
  constexpr int JW  = TT + 4;    // halo rows (pad 2 each side)
  constexpr int STR = 40;        // padded LDS stride
  __shared__ float xs[CIN * STR];
  const int b   = blockIdx.y;
  const int t0  = blockIdx.x * TT;
  const int tid = threadIdx.x;
  const float* xb = x + (size_t)b * T_ * CIN;
  for (int idx = tid; idx < JW * CIN; idx += 256) {
    int ci = idx % CIN;
    int j  = idx / CIN;
    int t  = t0 - 2 + j;
    xs[ci * STR + j] = (t >= 0 && t < T_) ? xb[(size_t)t * CIN + ci] : 0.f;
  }
  __syncthreads();
  const int co = tid;
  float acc[TT];
#pragma unroll
  for (int i = 0; i < TT; i++) acc[i] = 0.f;
  for (int ci = 0; ci < CIN; ci++) {
    float xv[JW];
    const float4* xp = (const float4*)&xs[ci * STR];
#pragma unroll
    for (int r = 0; r < JW / 4; r++) {
      float4 q = xp[r];
      xv[4*r+0] = q.x; xv[4*r+1] = q.y; xv[4*r+2] = q.z; xv[4*r+3] = q.w;
    }
#pragma unroll
    for (int k = 0; k < 5; k++) {
      float wv = w[((size_t)k * CIN + ci) * H_ + co];
#pragma unroll
      for (int i = 0; i < TT; i++) acc[i] = fmaf(xv[i + k], wv, acc[i]);
    }
  }
  const float bv = bias[co];
#pragma unroll
  for (int i = 0; i < TT; i++) {
    int t = t0 + i;
    if (t < T_) y[((size_t)b * T_ + t) * H_ + co] = tanhf(acc[i] + bv);
  }
}

// ---------------- W[b,t,s] = sum_h Wspec[b,t,h] * src_enc[b,s,h] --------
__global__ __launch_bounds__(256)
void einsum_ts(const float* __restrict__ A, const float* __restrict__ E,
               float* __restrict__ Wg)
{
  constexpr int GT = 128, GS = 64, KC = 16;
  __shared__ float As[KC][GT + 4];
  __shared__ float Bs[KC][GS + 4];
  const int b   = blockIdx.z;
  const int t0  = blockIdx.x * GT;
  const int s0  = blockIdx.y * GS;
  const int tid = threadIdx.x;
  const int tx  = tid & 15;
  const int ty  = tid >> 4;
  float4 acc[8];
#pragma unroll
  for (int i = 0; i < 8; i++) acc[i] = make_float4(0.f, 0.f, 0.f, 0.f);
  const float* Ab = A + (size_t)b * T_ * H_;
  const float* Eb = E + (size_t)b * S_ * H_;
  for (int kc = 0; kc < H_; kc += KC) {
#pragma unroll
    for (int r = 0; r < 2; r++) {
      int f4  = tid + 256 * r;
      int row = f4 >> 2;
      int c4  = f4 & 3;
      int t   = t0 + row;
      float4 v = make_float4(0, 0, 0, 0);
      if (t < T_) v = *(const float4*)&Ab[(size_t)t * H_ + kc + c4 * 4];
      As[c4*4+0][row] = v.x; As[c4*4+1][row] = v.y;
      As[c4*4+2][row] = v.z; As[c4*4+3][row] = v.w;
    }
    {
      int row = tid >> 2;
      int c4  = tid & 3;
      int s   = s0 + row;
      float4 v = make_float4(0, 0, 0, 0);
      if (s < S_) v = *(const float4*)&Eb[(size_t)s * H_ + kc + c4 * 4];
      Bs[c4*4+0][row] = v.x; Bs[c4*4+1][row] = v.y;
      Bs[c4*4+2][row] = v.z; Bs[c4*4+3][row] = v.w;
    }
    __syncthreads();
#pragma unroll
    for (int kk = 0; kk < KC; kk++) {
      float4 a0 = *(const float4*)&As[kk][ty * 8];
      float4 a1 = *(const float4*)&As[kk][ty * 8 + 4];
      float4 bb = *(const float4*)&Bs[kk][tx * 4];
      float av[8] = {a0.x, a0.y, a0.z, a0.w, a1.x, a1.y, a1.z, a1.w};
#pragma unroll
      for (int i = 0; i < 8; i++) {
        acc[i].x = fmaf(av[i], bb.x, acc[i].x);
        acc[i].y = fmaf(av[i], bb.y, acc[i].y);
        acc[i].z = fmaf(av[i], bb.z, acc[i].z);
        acc[i].w = fmaf(av[i], bb.w, acc[i].w);
      }
    }
    __syncthreads();
  }
  float* Wb = Wg + (size_t)b * T_ * S_;
  const int s = s0 + tx * 4;
#pragma unroll
  for (int i = 0; i < 8; i++) {
    int t = t0 + ty * 8 + i;
    if (t < T_ && s < S_) *(float4*)&Wb[(size_t)t * S_ + s] = acc[i];
  }
}

// ---------------- per-(b,s) column softmax stats over T ------------------
// Writes M + ln(L) into mu[b][0][s] (consumed then overwritten by dp).
__global__ __launch_bounds__(256)
void softmax_stats(const float* __restrict__ Wg, float* __restrict__ statsOut)
{
  const int b  = blockIdx.y;
  const int tx = threadIdx.x & 63;
  const int ty = threadIdx.x >> 6;            // 0..3
  const int s  = blockIdx.x * 64 + tx;
  const bool act = (s < S_);
  float m = -1e30f, l = 0.f;
  if (act) {
    const float* col = Wg + (size_t)b * T_ * S_ + s;
#pragma unroll 4
    for (int t = ty; t < T_; t += 4) {
      float v  = col[(size_t)t * S_];
      float nm = fmaxf(m, v);
      l = l * __expf(m - nm) + __expf(v - nm);
      m = nm;
    }
  }
  __shared__ float rm[4][64], rl[4][64];
  rm[ty][tx] = m; rl[ty][tx] = l;
  __syncthreads();
  if (ty == 0 && act) {
    float M = rm[0][tx];
#pragma unroll
    for (int q = 1; q < 4; q++) M = fmaxf(M, rm[q][tx]);
    float L = 0.f;
#pragma unroll
    for (int q = 0; q < 4; q++) L += rl[q][tx] * __expf(rm[q][tx] - M);
    float* st = statsOut + (size_t)b * T_ * S_;
    st[s] = M + __logf(L);                    // single fused stat
  }
}

// ---------------- monotonic-alignment Bayesian DP (1 wave / batch) -------
// Lane l owns s = 8l..8l+7 (lanes 0..49 active; 50..63 clamp to col 392 and
// never store). One __shfl_up per t-step; no barriers, no LDS. All row
// traffic is float4. Prefetch slots are indexed by literal constants only.
__global__ __launch_bounds__(64)
void dp_kernel3(float* __restrict__ Wal,       // [B,T,S] raw scores in, alignments out
                const float* __restrict__ Mk,  // mask [B,T,S]
                float* __restrict__ muOut,     // [B,T,S]; row 0 carries M+lnL on entry
                float2* __restrict__ piOut)    // [B,T,S,2]
{
  const int b = blockIdx.x;
  const int l = threadIdx.x;                   // 0..63
  const int s0raw = l * 8;
  const bool act = (s0raw < S_);               // lanes 0..49
  const int c0 = act ? s0raw : (S_ - 8);

  float*       alb = Wal   + (size_t)b * T_ * S_;
  const float* kb  = Mk    + (size_t)b * T_ * S_;
  float*       mub = muOut + (size_t)b * T_ * S_;
  float*       pib = (float*)(piOut + (size_t)b * T_ * S_);

  // stats (M + lnL) — read BEFORE any write to mu row 0
  float Ms[8];
  {
    float4 lo = *(const float4*)&mub[c0];
    float4 hi = *(const float4*)&mub[c0 + 4];
    Ms[0]=lo.x; Ms[1]=lo.y; Ms[2]=lo.z; Ms[3]=lo.w;
    Ms[4]=hi.x; Ms[5]=hi.y; Ms[6]=hi.z; Ms[7]=hi.w;
  }

  float m[8];

  // ---- t = 0 ----
  {
    float4 aLo = *(const float4*)&alb[c0];
    float4 aHi = *(const float4*)&alb[c0 + 4];
    float4 kLo = *(const float4*)&kb[c0];
    float4 kHi = *(const float4*)&kb[c0 + 4];
    float aj[8] = {aLo.x,aLo.y,aLo.z,aLo.w,aHi.x,aHi.y,aHi.z,aHi.w};
    float kj[8] = {kLo.x,kLo.y,kLo.z,kLo.w,kHi.x,kHi.y,kHi.z,kHi.w};
    float av[8];
#pragma unroll
    for (int j = 0; j < 8; j++) {
      av[j] = __expf(aj[j] - Ms[j]);
      m[j]  = av[j] * kj[j] + ((c0 + j) == 0 ? 0.f : NEGV);
    }
    if (act) {
      *(float4*)&alb[c0]     = make_float4(av[0],av[1],av[2],av[3]);
      *(float4*)&alb[c0 + 4] = make_float4(av[4],av[5],av[6],av[7]);
      *(float4*)&mub[c0]     = make_float4(m[0],m[1],m[2],m[3]);
      *(float4*)&mub[c0 + 4] = make_float4(m[4],m[5],m[6],m[7]);
      float* wp = pib + 2 * c0;
#pragma unroll
      for (int q = 0; q < 4; q++)
        *(float4*)&wp[4 * q] = make_float4(1.f, 0.f, 1.f, 0.f);
    }
  }

  float4 aL[4], aH[4], kL[4], kH[4];

#define LOADROW(slot, row)                                                  \
  { const float* ra_ = alb + (size_t)(row) * S_ + c0;                       \
    const float* rk_ = kb  + (size_t)(row) * S_ + c0;                       \
    aL[slot] = *(const float4*)ra_;  aH[slot] = *(const float4*)(ra_ + 4);  \
    kL[slot] = *(const float4*)rk_;  kH[slot] = *(const float4*)(rk_ + 4); }

#define DP_BODY(slot, t)                                                    \
  { float aj[8] = {aL[slot].x,aL[slot].y,aL[slot].z,aL[slot].w,             \
                   aH[slot].x,aH[slot].y,aH[slot].z,aH[slot].w};            \
    float kj[8] = {kL[slot].x,kL[slot].y,kL[slot].z,kL[slot].w,             \
                   kH[slot].x,kH[slot].y,kH[slot].z,kH[slot].w};

#define DP_TAIL(t)                                                          \
    float sh = __shfl_up(m[7], 1);                                          \
    if (l == 0) sh = NEGV;                                                  \
    float av[8], p0[8], p1[8];                                              \
    _Pragma("unroll")                                                       \
    for (int j = 7; j >= 0; j--) {                                          \
      av[j]      = __expf(aj[j] - Ms[j]);                                   \
      float w    = av[j] * kj[j];                                           \
      float prev = m[j];                                                    \
      float sft  = (j == 0) ? sh : m[j - 1];                                \
      float d    = prev - sft;                                              \
      float e    = __expf(-fabsf(d));                                       \
      float q    = 1.f + e;                                                 \
      float hi   = fmaxf(prev, sft);                                        \
      float lg   = __logf(q);                                               \
      float r;                                                              \
      asm("v_rcp_f32 %0, %1" : "=v"(r) : "v"(q));                           \
      float rr   = (d >= 0.f) ? r : 1.f - r;                                \
      p0[j] = rr; p1[j] = 1.f - rr;                                         \
      m[j] = w + hi + lg;                                                   \
    }                                                                       \
    if (act) {                                                              \
      float* wa_ = alb + (size_t)(t) * S_ + c0;                             \
      float* wm_ = mub + (size_t)(t) * S_ + c0;                             \
      float* wp_ = pib + (size_t)(t) * 2 * S_ + 2 * c0;                     \
      *(float4*)wa_       = make_float4(av[0],av[1],av[2],av[3]);           \
      *(float4*)(wa_ + 4) = make_float4(av[4],av[5],av[6],av[7]);           \
      *(float4*)wm_       = make_float4(m[0],m[1],m[2],m[3]);               \
      *(float4*)(wm_ + 4) = make_float4(m[4],m[5],m[6],m[7]);               \
      *(float4*)&wp_[0]   = make_float4(p0[0],p1[0],p0[1],p1[1]);           \
      *(float4*)&wp_[4]   = make_float4(p0[2],p1[2],p0[3],p1[3]);           \
      *(float4*)&wp_[8]   = make_float4(p0[4],p1[4],p0[5],p1[5]);           \
      *(float4*)&wp_[12]  = make_float4(p0[6],p1[6],p0[7],p1[7]);           \
    } }

// step with prefetch of row `prow` into the slot being consumed
#define STEPP(slot, t, prow) DP_BODY(slot, t) LOADROW(slot, prow) DP_TAIL(t)
// step without prefetch
#define STEPN(slot, t)       DP_BODY(slot, t)                     DP_TAIL(t)

  // initial prefetch: rows 1..4 into slots 0..3
  LOADROW(0, 1) LOADROW(1, 2) LOADROW(2, 3) LOADROW(3, 4)

  int t0 = 1;
  // main loop: compute rows t0..t0+3, prefetch t0+4..t0+7 (valid while t0+7 <= T_-1)
  for (; t0 + 7 <= T_ - 1; t0 += 4) {
    STEPP(0, t0 + 0, t0 + 4)
    STEPP(1, t0 + 1, t0 + 5)
    STEPP(2, t0 + 2, t0 + 6)
    STEPP(3, t0 + 3, t0 + 7)
  }
  // t0 == 1993: slots hold rows 1993..1996; rows 1997..1999 still to load
  STEPP(0, 1993, 1997)
  STEPP(1, 1994, 1998)
  STEPP(2, 1995, 1999)
  STEPN(3, 1996)
  STEPN(0, 1997)
  STEPN(1, 1998)
  STEPN(2, 1999)

#undef LOADROW
#undef DP_BODY
#undef DP_TAIL
#undef STEPP
#undef STEPN
}

// -------------------------------------------------------------------------
extern "C" void kernel_launch(void* const* d_in, const int* in_sizes, int n_in,
                              void* d_out, int out_size, void* d_ws, size_t ws_size,
                              hipStream_t stream)
{
  (void)in_sizes; (void)n_in; (void)out_size; (void)d_ws; (void)ws_size;
  const float* x   = (const float*)d_in[0];
  const float* enc = (const float*)d_in[1];
  const float* msk = (const float*)d_in[2];
  const float* w1  = (const float*)d_in[3];
  const float* b1  = (const float*)d_in[4];
  const float* w2  = (const float*)d_in[5];
  const float* b2  = (const float*)d_in[6];
  const float* w3  = (const float*)d_in[7];
  const float* b3  = (const float*)d_in[8];

  float* out = (float*)d_out;
  float* mu  = out;                       // [B,T,S]
  float* pi  = out + NMU;                 // [B,T,S,2]
  float* al  = out + NMU + NPI;           // [B,T,S]
  float* wsp = out + NMU + NPI + NMU;     // [B,T,H]
  float* h1  = pi;                        // scratch inside pi region (written last)
  float* h2  = pi + NWSP;

  dim3 cgrid((T_ + 31) / 32, B_);
  hipLaunchKernelGGL((conv1d_tanh<C0_>), cgrid, dim3(256), 0, stream, x,  w1, b1, h1);
  hipLaunchKernelGGL((conv1d_tanh<H_>),  cgrid, dim3(256), 0, stream, h1, w2, b2, h2);
  hipLaunchKernelGGL((conv1d_tanh<H_>),  cgrid, dim3(256), 0, stream, h2, w3, b3, wsp);
  hipLaunchKernelGGL(einsum_ts, dim3((T_ + 127) / 128, (S_ + 63) / 64, B_), dim3(256),
                     0, stream, wsp, enc, al);
  hipLaunchKernelGGL(softmax_stats, dim3((S_ + 63) / 64, B_), dim3(256), 0, stream, al, mu);
  hipLaunchKernelGGL(dp_kernel3, dim3(B_), dim3(64), 0, stream, al, msk, mu, (float2*)pi);
}

// Round 4
// 2512.904 us; speedup vs baseline: 1.4610x; 1.1938x over previous
//
#include <hip/hip_runtime.h>
#include <hip/hip_bf16.h>

#define B_ 32
#define T_ 2000
#define S_ 400
#define C0_ 80
#define H_ 256

static constexpr float NEGV = -1e9f;
static constexpr int NMU  = B_ * T_ * S_;       // 25,600,000
static constexpr int NPI  = 2 * NMU;            // 51,200,000
static constexpr int NWSP = B_ * T_ * H_;       // 16,384,000

// ---------------- conv1d (K=5, SAME) + bias + tanh ----------------------
template<int CIN>
__global__ __launch_bounds__(256)
void conv1d_tanh(const float* __restrict__ x, const float* __restrict__ w,
                 const float* __restrict__ bias, float* __restrict__ y)
{
  constexpr int TT  = 32;        // t rows per block
  constexpr int JW  = TT + 4;    // halo rows (pad 2 each side)
  constexpr int STR = 40;        // padded LDS stride
  __shared__ float xs[CIN * STR];
  const int b   = blockIdx.y;
  const int t0  = blockIdx.x * TT;
  const int tid = threadIdx.x;
  const float* xb = x + (size_t)b * T_ * CIN;
  for (int idx = tid; idx < JW * CIN; idx += 256) {
    int ci = idx % CIN;
    int j  = idx / CIN;
    int t  = t0 - 2 + j;
    xs[ci * STR + j] = (t >= 0 && t < T_) ? xb[(size_t)t * CIN + ci] : 0.f;
  }
  __syncthreads();
  const int co = tid;
  float acc[TT];
#pragma unroll
  for (int i = 0; i < TT; i++) acc[i] = 0.f;
  for (int ci = 0; ci < CIN; ci++) {
    float xv[JW];
    const float4* xp = (const float4*)&xs[ci * STR];
#pragma unroll
    for (int r = 0; r < JW / 4; r++) {
      float4 q = xp[r];
      xv[4*r+0] = q.x; xv[4*r+1] = q.y; xv[4*r+2] = q.z; xv[4*r+3] = q.w;
    }
#pragma unroll
    for (int k = 0; k < 5; k++) {
      float wv = w[((size_t)k * CIN + ci) * H_ + co];
#pragma unroll
      for (int i = 0; i < TT; i++) acc[i] = fmaf(xv[i + k], wv, acc[i]);
    }
  }
  const float bv = bias[co];
#pragma unroll
  for (int i = 0; i < TT; i++) {
    int t = t0 + i;
    if (t < T_) y[((size_t)b * T_ + t) * H_ + co] = tanhf(acc[i] + bv);
  }
}

// ---------------- W[b,t,s] = sum_h Wspec[b,t,h] * src_enc[b,s,h] --------
__global__ __launch_bounds__(256)
void einsum_ts(const float* __restrict__ A, const float* __restrict__ E,
               float* __restrict__ Wg)
{
  constexpr int GT = 128, GS = 64, KC = 16;
  __shared__ float As[KC][GT + 4];
  __shared__ float Bs[KC][GS + 4];
  const int b   = blockIdx.z;
  const int t0  = blockIdx.x * GT;
  const int s0  = blockIdx.y * GS;
  const int tid = threadIdx.x;
  const int tx  = tid & 15;
  const int ty  = tid >> 4;
  float4 acc[8];
#pragma unroll
  for (int i = 0; i < 8; i++) acc[i] = make_float4(0.f, 0.f, 0.f, 0.f);
  const float* Ab = A + (size_t)b * T_ * H_;
  const float* Eb = E + (size_t)b * S_ * H_;
  for (int kc = 0; kc < H_; kc += KC) {
#pragma unroll
    for (int r = 0; r < 2; r++) {
      int f4  = tid + 256 * r;
      int row = f4 >> 2;
      int c4  = f4 & 3;
      int t   = t0 + row;
      float4 v = make_float4(0, 0, 0, 0);
      if (t < T_) v = *(const float4*)&Ab[(size_t)t * H_ + kc + c4 * 4];
      As[c4*4+0][row] = v.x; As[c4*4+1][row] = v.y;
      As[c4*4+2][row] = v.z; As[c4*4+3][row] = v.w;
    }
    {
      int row = tid >> 2;
      int c4  = tid & 3;
      int s   = s0 + row;
      float4 v = make_float4(0, 0, 0, 0);
      if (s < S_) v = *(const float4*)&Eb[(size_t)s * H_ + kc + c4 * 4];
      Bs[c4*4+0][row] = v.x; Bs[c4*4+1][row] = v.y;
      Bs[c4*4+2][row] = v.z; Bs[c4*4+3][row] = v.w;
    }
    __syncthreads();
#pragma unroll
    for (int kk = 0; kk < KC; kk++) {
      float4 a0 = *(const float4*)&As[kk][ty * 8];
      float4 a1 = *(const float4*)&As[kk][ty * 8 + 4];
      float4 bb = *(const float4*)&Bs[kk][tx * 4];
      float av[8] = {a0.x, a0.y, a0.z, a0.w, a1.x, a1.y, a1.z, a1.w};
#pragma unroll
      for (int i = 0; i < 8; i++) {
        acc[i].x = fmaf(av[i], bb.x, acc[i].x);
        acc[i].y = fmaf(av[i], bb.y, acc[i].y);
        acc[i].z = fmaf(av[i], bb.z, acc[i].z);
        acc[i].w = fmaf(av[i], bb.w, acc[i].w);
      }
    }
    __syncthreads();
  }
  float* Wb = Wg + (size_t)b * T_ * S_;
  const int s = s0 + tx * 4;
#pragma unroll
  for (int i = 0; i < 8; i++) {
    int t = t0 + ty * 8 + i;
    if (t < T_ && s < S_) *(float4*)&Wb[(size_t)t * S_ + s] = acc[i];
  }
}

// ---------------- per-(b,s) column softmax stats over T ------------------
// Writes M + ln(L) into mu[b][0][s] (consumed then overwritten by dp).
__global__ __launch_bounds__(256)
void softmax_stats(const float* __restrict__ Wg, float* __restrict__ statsOut)
{
  const int b  = blockIdx.y;
  const int tx = threadIdx.x & 63;
  const int ty = threadIdx.x >> 6;            // 0..3
  const int s  = blockIdx.x * 64 + tx;
  const bool act = (s < S_);
  float m = -1e30f, l = 0.f;
  if (act) {
    const float* col = Wg + (size_t)b * T_ * S_ + s;
#pragma unroll 4
    for (int t = ty; t < T_; t += 4) {
      float v  = col[(size_t)t * S_];
      float nm = fmaxf(m, v);
      l = l * __expf(m - nm) + __expf(v - nm);
      m = nm;
    }
  }
  __shared__ float rm[4][64], rl[4][64];
  rm[ty][tx] = m; rl[ty][tx] = l;
  __syncthreads();
  if (ty == 0 && act) {
    float M = rm[0][tx];
#pragma unroll
    for (int q = 1; q < 4; q++) M = fmaxf(M, rm[q][tx]);
    float L = 0.f;
#pragma unroll
    for (int q = 0; q < 4; q++) L += rl[q][tx] * __expf(rm[q][tx] - M);
    float* st = statsOut + (size_t)b * T_ * S_;
    st[s] = M + __logf(L);                    // single fused stat
  }
}

// ---------------- alignment normalize + mask premultiply -----------------
// al_out = exp(raw - stat);  Wdp = al_out * mask  (Wdp -> pi-region scratch)
__global__ __launch_bounds__(256)
void norm_kernel(float* __restrict__ al,           // in: raw scores; out: alignments
                 const float* __restrict__ Mk,     // mask
                 const float* __restrict__ muStat, // [B,T,S]; row 0 = M+lnL
                 float* __restrict__ Wdp)          // [B,T,S] scratch
{
  const int gid = blockIdx.x * 256 + threadIdx.x;   // one float4 per thread
  if (gid >= NMU / 4) return;
  const int b   = gid / (T_ * S_ / 4);
  const int rem = gid - b * (T_ * S_ / 4);
  const int s4  = rem % (S_ / 4);
  const float4 st4 = *(const float4*)&muStat[(size_t)b * T_ * S_ + 4 * s4];
  float4 r = ((const float4*)al)[gid];
  float4 k = ((const float4*)Mk)[gid];
  float4 a;
  a.x = __expf(r.x - st4.x);
  a.y = __expf(r.y - st4.y);
  a.z = __expf(r.z - st4.z);
  a.w = __expf(r.w - st4.w);
  ((float4*)al)[gid]  = a;
  ((float4*)Wdp)[gid] = make_float4(a.x * k.x, a.y * k.y, a.z * k.z, a.w * k.w);
}

// ---------------- monotonic-alignment DP: mu only (1 wave / batch) -------
// Lane l owns s = 8l..8l+7 (lanes 0..49 active). One __shfl_up per t-step;
// no barriers, no LDS, literal-indexed prefetch slots, VGPRs uncapped.
__global__ __launch_bounds__(64, 1)
void dp_mu(const float* __restrict__ Wdp,   // [B,T,S] = alignments * mask
           float* __restrict__ muOut)       // [B,T,S]
{
  const int b = blockIdx.x;
  const int l = threadIdx.x;                   // 0..63
  const int s0raw = l * 8;
  const bool act = (s0raw < S_);               // lanes 0..49
  const int c0 = act ? s0raw : (S_ - 8);

  const float* wb  = Wdp   + (size_t)b * T_ * S_;
  float*       mub = muOut + (size_t)b * T_ * S_;

  float m[8];
  // ---- t = 0 ----
  {
    float4 lo = *(const float4*)&wb[c0];
    float4 hi = *(const float4*)&wb[c0 + 4];
    float w0[8] = {lo.x,lo.y,lo.z,lo.w,hi.x,hi.y,hi.z,hi.w};
#pragma unroll
    for (int j = 0; j < 8; j++) m[j] = w0[j] + ((c0 + j) == 0 ? 0.f : NEGV);
    if (act) {
      *(float4*)&mub[c0]     = make_float4(m[0],m[1],m[2],m[3]);
      *(float4*)&mub[c0 + 4] = make_float4(m[4],m[5],m[6],m[7]);
    }
  }

  float4 wL[4], wH[4];

#define LOADW(slot, row)                                                    \
  { const float* r_ = wb + (size_t)(row) * S_ + c0;                         \
    wL[slot] = *(const float4*)r_;  wH[slot] = *(const float4*)(r_ + 4); }

#define DPSTEP(slot, t, prow, doPF)                                         \
  { float wj[8] = {wL[slot].x,wL[slot].y,wL[slot].z,wL[slot].w,             \
                   wH[slot].x,wH[slot].y,wH[slot].z,wH[slot].w};            \
    if (doPF) LOADW(slot, prow)                                             \
    float sh = __shfl_up(m[7], 1);                                          \
    if (l == 0) sh = NEGV;                                                  \
    _Pragma("unroll")                                                       \
    for (int j = 7; j >= 0; j--) {                                          \
      float prev = m[j];                                                    \
      float sft  = (j == 0) ? sh : m[j - 1];                                \
      float d    = prev - sft;                                              \
      float e    = __expf(-fabsf(d));                                       \
      float lg   = __logf(1.f + e);                                         \
      float hi   = fmaxf(prev, sft);                                        \
      m[j] = wj[j] + hi + lg;                                               \
    }                                                                       \
    if (act) {                                                              \
      float* wm_ = mub + (size_t)(t) * S_ + c0;                             \
      *(float4*)wm_       = make_float4(m[0],m[1],m[2],m[3]);               \
      *(float4*)(wm_ + 4) = make_float4(m[4],m[5],m[6],m[7]);               \
    } }

  // initial prefetch: rows 1..4 into slots 0..3
  LOADW(0, 1) LOADW(1, 2) LOADW(2, 3) LOADW(3, 4)

  int t0 = 1;
  for (; t0 + 7 <= T_ - 1; t0 += 4) {
    DPSTEP(0, t0 + 0, t0 + 4, true)
    DPSTEP(1, t0 + 1, t0 + 5, true)
    DPSTEP(2, t0 + 2, t0 + 6, true)
    DPSTEP(3, t0 + 3, t0 + 7, true)
  }
  // t0 == 1993: slots hold rows 1993..1996; rows 1997..1999 still to load
  DPSTEP(0, 1993, 1997, true)
  DPSTEP(1, 1994, 1998, true)
  DPSTEP(2, 1995, 1999, true)
  DPSTEP(3, 1996, 0, false)
  DPSTEP(0, 1997, 0, false)
  DPSTEP(1, 1998, 0, false)
  DPSTEP(2, 1999, 0, false)

#undef LOADW
#undef DPSTEP
}

// ---------------- pi from consecutive mu rows (fully parallel) -----------
// pi[b,0,s] = (1,0); pi[b,t,s] = softmax([mu[t-1,s], mu[t-1,s-1]]), s-1<0 -> NEG
__global__ __launch_bounds__(256)
void pi_kernel(const float* __restrict__ mu, float* __restrict__ pi)
{
  const int gid = blockIdx.x * 256 + threadIdx.x;   // one float4 of mu-row per thread
  if (gid >= NMU / 4) return;
  const int b   = gid / (T_ * S_ / 4);
  const int rem = gid - b * (T_ * S_ / 4);
  const int t   = rem / (S_ / 4);
  const int s4  = rem - t * (S_ / 4);
  float* wp = pi + (size_t)gid * 8;
  if (t == 0) {
    *(float4*)wp       = make_float4(1.f, 0.f, 1.f, 0.f);
    *(float4*)(wp + 4) = make_float4(1.f, 0.f, 1.f, 0.f);
    return;
  }
  const float* row = mu + (size_t)b * T_ * S_ + (size_t)(t - 1) * S_;
  float4 v = *(const float4*)&row[4 * s4];
  float left = (s4 == 0) ? NEGV : row[4 * s4 - 1];
  float pv[4] = {v.x, v.y, v.z, v.w};
  float sf[4] = {left, v.x, v.y, v.z};
  float p0[4], p1[4];
#pragma unroll
  for (int i = 0; i < 4; i++) {
    float d = pv[i] - sf[i];
    float e = __expf(-fabsf(d));
    float q = 1.f + e;
    float r;
    asm("v_rcp_f32 %0, %1" : "=v"(r) : "v"(q));
    float rr = (d >= 0.f) ? r : 1.f - r;
    p0[i] = rr; p1[i] = 1.f - rr;
  }
  *(float4*)wp       = make_float4(p0[0], p1[0], p0[1], p1[1]);
  *(float4*)(wp + 4) = make_float4(p0[2], p1[2], p0[3], p1[3]);
}

// -------------------------------------------------------------------------
extern "C" void kernel_launch(void* const* d_in, const int* in_sizes, int n_in,
                              void* d_out, int out_size, void* d_ws, size_t ws_size,
                              hipStream_t stream)
{
  (void)in_sizes; (void)n_in; (void)out_size; (void)d_ws; (void)ws_size;
  const float* x   = (const float*)d_in[0];
  const float* enc = (const float*)d_in[1];
  const float* msk = (const float*)d_in[2];
  const float* w1  = (const float*)d_in[3];
  const float* b1  = (const float*)d_in[4];
  const float* w2  = (const float*)d_in[5];
  const float* b2  = (const float*)d_in[6];
  const float* w3  = (const float*)d_in[7];
  const float* b3  = (const float*)d_in[8];

  float* out = (float*)d_out;
  float* mu  = out;                       // [B,T,S]
  float* pi  = out + NMU;                 // [B,T,S,2]
  float* al  = out + NMU + NPI;           // [B,T,S]
  float* wsp = out + NMU + NPI + NMU;     // [B,T,H]
  float* h1  = pi;                        // conv scratch inside pi region
  float* h2  = pi + NWSP;
  float* wdp = pi;                        // DP weights scratch (pi written last)

  dim3 cgrid((T_ + 31) / 32, B_);
  hipLaunchKernelGGL((conv1d_tanh<C0_>), cgrid, dim3(256), 0, stream, x,  w1, b1, h1);
  hipLaunchKernelGGL((conv1d_tanh<H_>),  cgrid, dim3(256), 0, stream, h1, w2, b2, h2);
  hipLaunchKernelGGL((conv1d_tanh<H_>),  cgrid, dim3(256), 0, stream, h2, w3, b3, wsp);
  hipLaunchKernelGGL(einsum_ts, dim3((T_ + 127) / 128, (S_ + 63) / 64, B_), dim3(256),
                     0, stream, wsp, enc, al);
  hipLaunchKernelGGL(softmax_stats, dim3((S_ + 63) / 64, B_), dim3(256), 0, stream, al, mu);
  hipLaunchKernelGGL(norm_kernel, dim3(NMU / 4 / 256), dim3(256), 0, stream, al, msk, mu, wdp);
  hipLaunchKernelGGL(dp_mu, dim3(B_), dim3(64), 0, stream, wdp, mu);
  hipLaunchKernelGGL(pi_kernel, dim3(NMU / 4 / 256), dim3(256), 0, stream, mu, pi);
}

// Round 5
// 2474.540 us; speedup vs baseline: 1.4836x; 1.0155x over previous
//
#include <hip/hip_runtime.h>
#include <hip/hip_bf16.h>

#define B_ 32
#define T_ 2000
#define S_ 400
#define C0_ 80
#define H_ 256

static constexpr float NEGV = -1e9f;
static constexpr int NMU  = B_ * T_ * S_;       // 25,600,000
static constexpr int NPI  = 2 * NMU;            // 51,200,000
static constexpr int NWSP = B_ * T_ * H_;       // 16,384,000

// ---------------- conv1d (K=5, SAME) + bias + tanh ----------------------
template<int CIN>
__global__ __launch_bounds__(256)
void conv1d_tanh(const float* __restrict__ x, const float* __restrict__ w,
                 const float* __restrict__ bias, float* __restrict__ y)
{
  constexpr int TT  = 32;        // t rows per block
  constexpr int JW  = TT + 4;    // halo rows (pad 2 each side)
  constexpr int STR = 40;        // padded LDS stride
  __shared__ float xs[CIN * STR];
  const int b   = blockIdx.y;
  const int t0  = blockIdx.x * TT;
  const int tid = threadIdx.x;
  const float* xb = x + (size_t)b * T_ * CIN;
  for (int idx = tid; idx < JW * CIN; idx += 256) {
    int ci = idx % CIN;
    int j  = idx / CIN;
    int t  = t0 - 2 + j;
    xs[ci * STR + j] = (t >= 0 && t < T_) ? xb[(size_t)t * CIN + ci] : 0.f;
  }
  __syncthreads();
  const int co = tid;
  float acc[TT];
#pragma unroll
  for (int i = 0; i < TT; i++) acc[i] = 0.f;
  for (int ci = 0; ci < CIN; ci++) {
    float xv[JW];
    const float4* xp = (const float4*)&xs[ci * STR];
#pragma unroll
    for (int r = 0; r < JW / 4; r++) {
      float4 q = xp[r];
      xv[4*r+0] = q.x; xv[4*r+1] = q.y; xv[4*r+2] = q.z; xv[4*r+3] = q.w;
    }
#pragma unroll
    for (int k = 0; k < 5; k++) {
      float wv = w[((size_t)k * CIN + ci) * H_ + co];
#pragma unroll
      for (int i = 0; i < TT; i++) acc[i] = fmaf(xv[i + k], wv, acc[i]);
    }
  }
  const float bv = bias[co];
#pragma unroll
  for (int i = 0; i < TT; i++) {
    int t = t0 + i;
    if (t < T_) y[((size_t)b * T_ + t) * H_ + co] = tanhf(acc[i] + bv);
  }
}

// ---------------- W[b,t,s] = sum_h Wspec[b,t,h] * src_enc[b,s,h] --------
__global__ __launch_bounds__(256)
void einsum_ts(const float* __restrict__ A, const float* __restrict__ E,
               float* __restrict__ Wg)
{
  constexpr int GT = 128, GS = 64, KC = 16;
  __shared__ float As[KC][GT + 4];
  __shared__ float Bs[KC][GS + 4];
  const int b   = blockIdx.z;
  const int t0  = blockIdx.x * GT;
  const int s0  = blockIdx.y * GS;
  const int tid = threadIdx.x;
  const int tx  = tid & 15;
  const int ty  = tid >> 4;
  float4 acc[8];
#pragma unroll
  for (int i = 0; i < 8; i++) acc[i] = make_float4(0.f, 0.f, 0.f, 0.f);
  const float* Ab = A + (size_t)b * T_ * H_;
  const float* Eb = E + (size_t)b * S_ * H_;
  for (int kc = 0; kc < H_; kc += KC) {
#pragma unroll
    for (int r = 0; r < 2; r++) {
      int f4  = tid + 256 * r;
      int row = f4 >> 2;
      int c4  = f4 & 3;
      int t   = t0 + row;
      float4 v = make_float4(0, 0, 0, 0);
      if (t < T_) v = *(const float4*)&Ab[(size_t)t * H_ + kc + c4 * 4];
      As[c4*4+0][row] = v.x; As[c4*4+1][row] = v.y;
      As[c4*4+2][row] = v.z; As[c4*4+3][row] = v.w;
    }
    {
      int row = tid >> 2;
      int c4  = tid & 3;
      int s   = s0 + row;
      float4 v = make_float4(0, 0, 0, 0);
      if (s < S_) v = *(const float4*)&Eb[(size_t)s * H_ + kc + c4 * 4];
      Bs[c4*4+0][row] = v.x; Bs[c4*4+1][row] = v.y;
      Bs[c4*4+2][row] = v.z; Bs[c4*4+3][row] = v.w;
    }
    __syncthreads();
#pragma unroll
    for (int kk = 0; kk < KC; kk++) {
      float4 a0 = *(const float4*)&As[kk][ty * 8];
      float4 a1 = *(const float4*)&As[kk][ty * 8 + 4];
      float4 bb = *(const float4*)&Bs[kk][tx * 4];
      float av[8] = {a0.x, a0.y, a0.z, a0.w, a1.x, a1.y, a1.z, a1.w};
#pragma unroll
      for (int i = 0; i < 8; i++) {
        acc[i].x = fmaf(av[i], bb.x, acc[i].x);
        acc[i].y = fmaf(av[i], bb.y, acc[i].y);
        acc[i].z = fmaf(av[i], bb.z, acc[i].z);
        acc[i].w = fmaf(av[i], bb.w, acc[i].w);
      }
    }
    __syncthreads();
  }
  float* Wb = Wg + (size_t)b * T_ * S_;
  const int s = s0 + tx * 4;
#pragma unroll
  for (int i = 0; i < 8; i++) {
    int t = t0 + ty * 8 + i;
    if (t < T_ && s < S_) *(float4*)&Wb[(size_t)t * S_ + s] = acc[i];
  }
}

// ---------------- per-(b,s) column softmax stats over T ------------------
// Writes M + ln(L) into mu[b][0][s] (consumed then overwritten by dp).
__global__ __launch_bounds__(256)
void softmax_stats(const float* __restrict__ Wg, float* __restrict__ statsOut)
{
  const int b  = blockIdx.y;
  const int tx = threadIdx.x & 63;
  const int ty = threadIdx.x >> 6;            // 0..3
  const int s  = blockIdx.x * 64 + tx;
  const bool act = (s < S_);
  float m = -1e30f, l = 0.f;
  if (act) {
    const float* col = Wg + (size_t)b * T_ * S_ + s;
#pragma unroll 4
    for (int t = ty; t < T_; t += 4) {
      float v  = col[(size_t)t * S_];
      float nm = fmaxf(m, v);
      l = l * __expf(m - nm) + __expf(v - nm);
      m = nm;
    }
  }
  __shared__ float rm[4][64], rl[4][64];
  rm[ty][tx] = m; rl[ty][tx] = l;
  __syncthreads();
  if (ty == 0 && act) {
    float M = rm[0][tx];
#pragma unroll
    for (int q = 1; q < 4; q++) M = fmaxf(M, rm[q][tx]);
    float L = 0.f;
#pragma unroll
    for (int q = 0; q < 4; q++) L += rl[q][tx] * __expf(rm[q][tx] - M);
    float* st = statsOut + (size_t)b * T_ * S_;
    st[s] = M + __logf(L);                    // single fused stat
  }
}

// ---------------- alignment normalize + mask premultiply -----------------
// al_out = exp(raw - stat);  Wdp = al_out * mask  (Wdp -> pi-region scratch)
__global__ __launch_bounds__(256)
void norm_kernel(float* __restrict__ al,           // in: raw scores; out: alignments
                 const float* __restrict__ Mk,     // mask
                 const float* __restrict__ muStat, // [B,T,S]; row 0 = M+lnL
                 float* __restrict__ Wdp)          // [B,T,S] scratch
{
  const int gid = blockIdx.x * 256 + threadIdx.x;   // one float4 per thread
  if (gid >= NMU / 4) return;
  const int b   = gid / (T_ * S_ / 4);
  const int rem = gid - b * (T_ * S_ / 4);
  const int s4  = rem % (S_ / 4);
  const float4 st4 = *(const float4*)&muStat[(size_t)b * T_ * S_ + 4 * s4];
  float4 r = ((const float4*)al)[gid];
  float4 k = ((const float4*)Mk)[gid];
  float4 a;
  a.x = __expf(r.x - st4.x);
  a.y = __expf(r.y - st4.y);
  a.z = __expf(r.z - st4.z);
  a.w = __expf(r.w - st4.w);
  ((float4*)al)[gid]  = a;
  ((float4*)Wdp)[gid] = make_float4(a.x * k.x, a.y * k.y, a.z * k.z, a.w * k.w);
}

// ---------------- monotonic-alignment DP: producer/consumer --------------
// Block = 2 waves per batch. Wave 1: DMA-stages Wdp rows into a 2-chunk LDS
// ring via global_load_lds (no regs -> compiler can't de-pipeline). Wave 0:
// runs the serial DP from LDS; lane l owns s=8l..8l+7, one __shfl_up/step.
#define LDSDMA(ldsaddr, gaddr)                                              \
  __builtin_amdgcn_global_load_lds(                                         \
      (const __attribute__((address_space(1))) void*)(gaddr),               \
      (__attribute__((address_space(3))) void*)(ldsaddr), 16, 0, 0)

__global__ __launch_bounds__(128, 1)
void dp_mu2(const float* __restrict__ Wdp,   // [B,T,S] = alignments * mask
            float* __restrict__ muOut)       // [B,T,S]
{
  constexpr int CK  = 20;                    // rows per chunk
  constexpr int NCH = T_ / CK;               // 100
  __shared__ float buf[2 * CK * S_];         // 64 000 B ring
  const int b    = blockIdx.x;
  const int wave = threadIdx.x >> 6;
  const int l    = threadIdx.x & 63;
  const int s0raw = l * 8;
  const bool act = (s0raw < S_);             // lanes 0..49
  const int c0 = act ? s0raw : (S_ - 8);

  const float* wb  = Wdp   + (size_t)b * T_ * S_;
  float*       mub = muOut + (size_t)b * T_ * S_;

  float m[8];
#pragma unroll
  for (int j = 0; j < 8; j++) m[j] = NEGV;

#define DPMATH(cl, chh, t)                                                  \
  { float wj[8] = {cl.x,cl.y,cl.z,cl.w,chh.x,chh.y,chh.z,chh.w};            \
    float sh = __shfl_up(m[7], 1);                                          \
    if (l == 0) sh = NEGV;                                                  \
    _Pragma("unroll")                                                       \
    for (int j = 7; j >= 0; j--) {                                          \
      float prev = m[j];                                                    \
      float sft  = (j == 0) ? sh : m[j - 1];                                \
      float d    = prev - sft;                                              \
      float e    = __expf(-fabsf(d));                                       \
      float lg   = __logf(1.f + e);                                         \
      float hi   = fmaxf(prev, sft);                                        \
      m[j] = wj[j] + hi + lg;                                               \
    }                                                                       \
    if (act) {                                                              \
      float* wm_ = mub + (size_t)(t) * S_ + c0;                             \
      *(float4*)wm_       = make_float4(m[0],m[1],m[2],m[3]);               \
      *(float4*)(wm_ + 4) = make_float4(m[4],m[5],m[6],m[7]);               \
    } }

  auto do_chunk = [&](int cc) {
    const float* lrow = buf + (size_t)(cc & 1) * CK * S_;
    const int tb = cc * CK;
    float4 aL, aH, bL, bH;
#define LDA(rr) { const float* q_ = lrow + (rr) * S_ + c0;                  \
                  aL = *(const float4*)q_; aH = *(const float4*)(q_ + 4); }
#define LDB(rr) { const float* q_ = lrow + (rr) * S_ + c0;                  \
                  bL = *(const float4*)q_; bH = *(const float4*)(q_ + 4); }
#define ROW_A(r) { float4 cl = aL, chh = aH;                                \
                   if ((r) + 2 < CK) LDA((r) + 2)                           \
                   DPMATH(cl, chh, tb + (r)) }
#define ROW_B(r) { float4 cl = bL, chh = bH;                                \
                   if ((r) + 2 < CK) LDB((r) + 2)                           \
                   DPMATH(cl, chh, tb + (r)) }
    LDA(0) LDB(1)
    // row 0 of chunk 0 is the DP base case
    { float4 cl = aL, chh = aH;
      LDA(2)
      if (tb == 0) {
        float wj[8] = {cl.x,cl.y,cl.z,cl.w,chh.x,chh.y,chh.z,chh.w};
#pragma unroll
        for (int j = 0; j < 8; j++) m[j] = wj[j] + ((c0 + j) == 0 ? 0.f : NEGV);
        if (act) {
          *(float4*)&mub[c0]     = make_float4(m[0],m[1],m[2],m[3]);
          *(float4*)&mub[c0 + 4] = make_float4(m[4],m[5],m[6],m[7]);
        }
      } else {
        DPMATH(cl, chh, tb)
      }
    }
    ROW_B(1)  ROW_A(2)  ROW_B(3)  ROW_A(4)  ROW_B(5)  ROW_A(6)  ROW_B(7)
    ROW_A(8)  ROW_B(9)  ROW_A(10) ROW_B(11) ROW_A(12) ROW_B(13) ROW_A(14)
    ROW_B(15) ROW_A(16) ROW_B(17) ROW_A(18) ROW_B(19)
#undef LDA
#undef LDB
#undef ROW_A
#undef ROW_B
  };

  for (int c = 0; c < NCH; ++c) {
    if (wave == 1) {
      // producer: DMA chunk c rows into buf[c&1] (1600 B per row)
      char* lb = (char*)buf + (size_t)(c & 1) * CK * S_ * 4;
      const int tb = c * CK;
#pragma unroll 4
      for (int r = 0; r < CK; ++r) {
        const char* src = (const char*)(wb + (size_t)(tb + r) * S_);
        LDSDMA(lb + r * 1600,        src + (size_t)l * 16);
        if (l < 36)
          LDSDMA(lb + r * 1600 + 1024, src + 1024 + (size_t)l * 16);
      }
    } else if (c > 0) {
      do_chunk(c - 1);
    }
    __syncthreads();
  }
  if (wave == 0) do_chunk(NCH - 1);

#undef DPMATH
}

// ---------------- pi from consecutive mu rows (fully parallel) -----------
// pi[b,0,s] = (1,0); pi[b,t,s] = softmax([mu[t-1,s], mu[t-1,s-1]]), s-1<0 -> NEG
__global__ __launch_bounds__(256)
void pi_kernel(const float* __restrict__ mu, float* __restrict__ pi)
{
  const int gid = blockIdx.x * 256 + threadIdx.x;   // one float4 of mu-row per thread
  if (gid >= NMU / 4) return;
  const int b   = gid / (T_ * S_ / 4);
  const int rem = gid - b * (T_ * S_ / 4);
  const int t   = rem / (S_ / 4);
  const int s4  = rem - t * (S_ / 4);
  float* wp = pi + (size_t)gid * 8;
  if (t == 0) {
    *(float4*)wp       = make_float4(1.f, 0.f, 1.f, 0.f);
    *(float4*)(wp + 4) = make_float4(1.f, 0.f, 1.f, 0.f);
    return;
  }
  const float* row = mu + (size_t)b * T_ * S_ + (size_t)(t - 1) * S_;
  float4 v = *(const float4*)&row[4 * s4];
  float left = (s4 == 0) ? NEGV : row[4 * s4 - 1];
  float pv[4] = {v.x, v.y, v.z, v.w};
  float sf[4] = {left, v.x, v.y, v.z};
  float p0[4], p1[4];
#pragma unroll
  for (int i = 0; i < 4; i++) {
    float d = pv[i] - sf[i];
    float e = __expf(-fabsf(d));
    float q = 1.f + e;
    float r;
    asm("v_rcp_f32 %0, %1" : "=v"(r) : "v"(q));
    float rr = (d >= 0.f) ? r : 1.f - r;
    p0[i] = rr; p1[i] = 1.f - rr;
  }
  *(float4*)wp       = make_float4(p0[0], p1[0], p0[1], p1[1]);
  *(float4*)(wp + 4) = make_float4(p0[2], p1[2], p0[3], p1[3]);
}

// -------------------------------------------------------------------------
extern "C" void kernel_launch(void* const* d_in, const int* in_sizes, int n_in,
                              void* d_out, int out_size, void* d_ws, size_t ws_size,
                              hipStream_t stream)
{
  (void)in_sizes; (void)n_in; (void)out_size; (void)d_ws; (void)ws_size;
  const float* x   = (const float*)d_in[0];
  const float* enc = (const float*)d_in[1];
  const float* msk = (const float*)d_in[2];
  const float* w1  = (const float*)d_in[3];
  const float* b1  = (const float*)d_in[4];
  const float* w2  = (const float*)d_in[5];
  const float* b2  = (const float*)d_in[6];
  const float* w3  = (const float*)d_in[7];
  const float* b3  = (const float*)d_in[8];

  float* out = (float*)d_out;
  float* mu  = out;                       // [B,T,S]
  float* pi  = out + NMU;                 // [B,T,S,2]
  float* al  = out + NMU + NPI;           // [B,T,S]
  float* wsp = out + NMU + NPI + NMU;     // [B,T,H]
  float* h1  = pi;                        // conv scratch inside pi region
  float* h2  = pi + NWSP;
  float* wdp = pi;                        // DP weights scratch (pi written last)

  dim3 cgrid((T_ + 31) / 32, B_);
  hipLaunchKernelGGL((conv1d_tanh<C0_>), cgrid, dim3(256), 0, stream, x,  w1, b1, h1);
  hipLaunchKernelGGL((conv1d_tanh<H_>),  cgrid, dim3(256), 0, stream, h1, w2, b2, h2);
  hipLaunchKernelGGL((conv1d_tanh<H_>),  cgrid, dim3(256), 0, stream, h2, w3, b3, wsp);
  hipLaunchKernelGGL(einsum_ts, dim3((T_ + 127) / 128, (S_ + 63) / 64, B_), dim3(256),
                     0, stream, wsp, enc, al);
  hipLaunchKernelGGL(softmax_stats, dim3((S_ + 63) / 64, B_), dim3(256), 0, stream, al, mu);
  hipLaunchKernelGGL(norm_kernel, dim3(NMU / 4 / 256), dim3(256), 0, stream, al, msk, mu, wdp);
  hipLaunchKernelGGL(dp_mu2, dim3(B_), dim3(128), 0, stream, wdp, mu);
  hipLaunchKernelGGL(pi_kernel, dim3(NMU / 4 / 256), dim3(256), 0, stream, mu, pi);
}